// Round 2
// baseline (26020.871 us; speedup 1.0000x reference)
//
#include <hip/hip_runtime.h>
#include <math.h>

#define NPTS   8192
#define NB     2
#define NROWS  (NB*NPTS)       // 16384 rows per direction
#define CHUNK  1024
#define ROWS_PER_BLOCK 16
#define ROWS_PER_WAVE  4
#define BLURF  0.001f
#define LOG2E  1.4426950408889634f
#define LN2F   0.6931471805599453f
#define BLOGF  (-9.010913347279288f)   // -log(8192)

// ---------------------------------------------------------------- diameter
__global__ __launch_bounds__(1024) void minmax_kernel(
    const float* __restrict__ x, const float* __restrict__ y,
    float* __restrict__ diam_out)
{
    int tid = threadIdx.x;
    float mx[3] = {-INFINITY, -INFINITY, -INFINITY};
    float mn[3] = { INFINITY,  INFINITY,  INFINITY};
    for (int p = tid; p < NROWS; p += 1024) {
        #pragma unroll
        for (int d = 0; d < 3; ++d) {
            float a = x[p*3+d], b = y[p*3+d];
            mx[d] = fmaxf(mx[d], fmaxf(a, b));
            mn[d] = fminf(mn[d], fminf(a, b));
        }
    }
    #pragma unroll
    for (int off = 32; off >= 1; off >>= 1) {
        #pragma unroll
        for (int d = 0; d < 3; ++d) {
            mx[d] = fmaxf(mx[d], __shfl_xor(mx[d], off));
            mn[d] = fminf(mn[d], __shfl_xor(mn[d], off));
        }
    }
    __shared__ float smx[16][3], smn[16][3];
    int wid = tid >> 6, lane = tid & 63;
    if (lane == 0) {
        #pragma unroll
        for (int d = 0; d < 3; ++d) { smx[wid][d] = mx[d]; smn[wid][d] = mn[d]; }
    }
    __syncthreads();
    if (tid == 0) {
        float dm = 0.0f;
        #pragma unroll
        for (int d = 0; d < 3; ++d) {
            float a = -INFINITY, b = INFINITY;
            for (int w = 0; w < 16; ++w) {
                a = fmaxf(a, smx[w][d]); b = fminf(b, smn[w][d]);
            }
            dm = fmaxf(dm, a - b);
        }
        diam_out[0] = dm;
    }
}

// ------------------------------------------------- pack points into float4
__global__ __launch_bounds__(256) void pack_pts_kernel(
    const float* __restrict__ x, const float* __restrict__ y,
    float4* __restrict__ px4, float4* __restrict__ py4)
{
    int gid = blockIdx.x * 256 + threadIdx.x;   // 0..32767
    int sel = gid >> 14;
    int idx = gid & 16383;
    const float* p = sel ? y : x;
    float4 o;
    o.x = p[idx*3+0]; o.y = p[idx*3+1]; o.z = p[idx*3+2]; o.w = 0.0f;
    (sel ? py4 : px4)[idx] = o;
}

// ------------------------------------------------------------- softmin pass
// out[b,i] = -eps * ln2 * log2( sum_j 2^{h2[j] - C_ij * log2e/eps} ) (LSE-stable)
// dir 0: rows = x, cols = y, h = g   |  dir 1: rows = y, cols = x, h = f
__global__ __launch_bounds__(256) void softmin_kernel(
    const float* __restrict__ rows0, const float* __restrict__ rows1,
    const float4* __restrict__ cols0, const float4* __restrict__ cols1,
    const float* __restrict__ h0, const float* __restrict__ h1,
    const float* __restrict__ old0, const float* __restrict__ old1,
    float* __restrict__ out0, float* __restrict__ out1,
    int do_avg, const float* __restrict__ diam_ptr, float scale_k)
{
    __shared__ float4 lds[CHUNK];
    const int dir = blockIdx.z;
    const float*  rows = dir ? rows1 : rows0;
    const float4* cols = dir ? cols1 : cols0;
    const float*  hp   = dir ? h1   : h0;
    const float*  oldf = dir ? old1 : old0;
    float*        outf = dir ? out1 : out0;

    const float diam    = diam_ptr[0];
    const float eps     = fmaxf(diam * scale_k, BLURF);
    const float inv_eps = 1.0f / eps;
    const float nie2    = -LOG2E * inv_eps;

    const int tid  = threadIdx.x, lane = tid & 63, wid = tid >> 6;
    const int i0   = blockIdx.x * ROWS_PER_BLOCK;
    const int b    = i0 >> 13;
    const int ib   = (i0 & (NPTS-1)) + wid * ROWS_PER_WAVE;
    const int rowbase = b * NPTS + ib;

    float px[4], py[4], pz[4];
    #pragma unroll
    for (int r = 0; r < 4; ++r) {
        int o = (rowbase + r) * 3;
        px[r] = rows[o]; py[r] = rows[o+1]; pz[r] = rows[o+2];
    }

    float m[4], s[4];
    #pragma unroll
    for (int r = 0; r < 4; ++r) { m[r] = -INFINITY; s[r] = 0.0f; }

    const float4* csrc = cols + b * NPTS;
    const float*  hsrc = hp ? (hp + b * NPTS) : nullptr;

    for (int c0 = 0; c0 < NPTS; c0 += CHUNK) {
        __syncthreads();
        for (int t = tid; t < CHUNK; t += 256) {
            float4 p = csrc[c0 + t];
            float hv = hsrc ? hsrc[c0 + t] * inv_eps : 0.0f;
            p.w = (BLOGF + hv) * LOG2E;   // h2[j] in base-2 domain
            lds[t] = p;
        }
        __syncthreads();
        #pragma unroll
        for (int t = 0; t < CHUNK/64; ++t) {
            float4 p = lds[t*64 + lane];
            #pragma unroll
            for (int r = 0; r < 4; ++r) {
                float dx = px[r]-p.x, dy = py[r]-p.y, dz = pz[r]-p.z;
                float sq = fmaf(dx,dx,fmaf(dy,dy,dz*dz));
                float c  = sqrtf(fmaxf(sq, 1e-12f));
                float v  = fmaf(c, nie2, p.w);
                float mu = fmaxf(m[r], v);
                s[r] = fmaf(s[r], exp2f(m[r]-mu), exp2f(v-mu));
                m[r] = mu;
            }
        }
    }

    // cross-lane LSE merge (64-lane butterfly)
    #pragma unroll
    for (int r = 0; r < 4; ++r) {
        float mm = m[r], ss = s[r];
        #pragma unroll
        for (int off = 32; off >= 1; off >>= 1) {
            float mo = __shfl_xor(mm, off);
            float so = __shfl_xor(ss, off);
            float mu = fmaxf(mm, mo);
            ss = fmaf(ss, exp2f(mm-mu), so * exp2f(mo-mu));
            mm = mu;
        }
        m[r] = mm; s[r] = ss;
    }

    if (lane == 0) {
        #pragma unroll
        for (int r = 0; r < 4; ++r) {
            float res = -eps * LN2F * (m[r] + log2f(s[r]));
            int oidx = rowbase + r;
            if (do_avg) res = 0.5f * (oldf[oidx] + res);
            outf[oidx] = res;
        }
    }
}

// ----------------------------------------------------------------- reduce
__global__ __launch_bounds__(1024) void reduce_kernel(
    const float* __restrict__ f, const float* __restrict__ g,
    float* __restrict__ out)
{
    int tid = threadIdx.x;
    float acc = 0.0f;
    for (int i = tid; i < NROWS; i += 1024) acc += f[i] + g[i];
    #pragma unroll
    for (int off = 32; off >= 1; off >>= 1) acc += __shfl_xor(acc, off);
    __shared__ float sw[16];
    int wid = tid >> 6, lane = tid & 63;
    if (lane == 0) sw[wid] = acc;
    __syncthreads();
    if (tid == 0) {
        float t = 0.0f;
        for (int w = 0; w < 16; ++w) t += sw[w];
        out[0] = t * (1.0f / (float)NROWS);   // mean over B of (sum a*f + sum b*g)
    }
}

// ----------------------------------------------------------------- launch
extern "C" void kernel_launch(void* const* d_in, const int* in_sizes, int n_in,
                              void* d_out, int out_size, void* d_ws, size_t ws_size,
                              hipStream_t stream)
{
    const float* x = (const float*)d_in[0];
    const float* y = (const float*)d_in[1];
    float* out = (float*)d_out;
    float* ws  = (float*)d_ws;

    float* diam = ws;                    // [16] (aligned pad)
    float* fa = ws + 16;                 // [16384]
    float* ga = fa + NROWS;
    float* fb = ga + NROWS;
    float* gb = fb + NROWS;
    float4* px4 = (float4*)(gb + NROWS); // 16384 float4 (offset 16B-aligned)
    float4* py4 = px4 + NROWS;

    minmax_kernel<<<1, 1024, 0, stream>>>(x, y, diam);
    pack_pts_kernel<<<(NROWS*2)/256, 256, 0, stream>>>(x, y, px4, py4);

    dim3 sgrid(NROWS/ROWS_PER_BLOCK, 1, 2);

    // init: f0 = softmin(eps0, Cxy, b_log), g0 = softmin(eps0, Cyx, a_log)
    softmin_kernel<<<sgrid, 256, 0, stream>>>(x, y, py4, px4,
        nullptr, nullptr, nullptr, nullptr, fa, ga, 0, diam, 1.0f);

    // 96 Jacobi steps with eps annealing: eps_k = max(diam * 0.9^k, blur)
    double sk = 1.0;
    for (int k = 0; k < 96; ++k) {
        softmin_kernel<<<sgrid, 256, 0, stream>>>(x, y, py4, px4,
            ga, fa, fa, ga, fb, gb, 1, diam, (float)sk);
        float* t;
        t = fa; fa = fb; fb = t;
        t = ga; ga = gb; gb = t;
        sk *= 0.9;
    }

    // final extrapolation at eps = blur (scale 0 -> fmax picks BLUR)
    softmin_kernel<<<sgrid, 256, 0, stream>>>(x, y, py4, px4,
        ga, fa, nullptr, nullptr, fb, gb, 0, diam, 0.0f);

    reduce_kernel<<<1, 1024, 0, stream>>>(fb, gb, out);
}

// Round 3
// 14045.595 us; speedup vs baseline: 1.8526x; 1.8526x over previous
//
#include <hip/hip_runtime.h>
#include <math.h>

#define NPTS   8192
#define NB     2
#define NROWS  (NB*NPTS)       // 16384 rows per direction
#define CHUNK  1024
#define ROWS_PER_BLOCK 16
#define ROWS_PER_WAVE  4
#define BLURF  0.001f
#define LOG2E  1.4426950408889634f
#define LN2F   0.6931471805599453f
#define BLOGF  (-9.010913347279288f)   // -log(8192)

#if __has_builtin(__builtin_amdgcn_sqrtf)
#define FAST_SQRT(x) __builtin_amdgcn_sqrtf(x)
#else
#define FAST_SQRT(x) sqrtf(x)
#endif

// ---------------------------------------------------------------- diameter
__global__ __launch_bounds__(1024) void minmax_kernel(
    const float* __restrict__ x, const float* __restrict__ y,
    float* __restrict__ diam_out)
{
    int tid = threadIdx.x;
    float mx[3] = {-INFINITY, -INFINITY, -INFINITY};
    float mn[3] = { INFINITY,  INFINITY,  INFINITY};
    for (int p = tid; p < NROWS; p += 1024) {
        #pragma unroll
        for (int d = 0; d < 3; ++d) {
            float a = x[p*3+d], b = y[p*3+d];
            mx[d] = fmaxf(mx[d], fmaxf(a, b));
            mn[d] = fminf(mn[d], fminf(a, b));
        }
    }
    #pragma unroll
    for (int off = 32; off >= 1; off >>= 1) {
        #pragma unroll
        for (int d = 0; d < 3; ++d) {
            mx[d] = fmaxf(mx[d], __shfl_xor(mx[d], off));
            mn[d] = fminf(mn[d], __shfl_xor(mn[d], off));
        }
    }
    __shared__ float smx[16][3], smn[16][3];
    int wid = tid >> 6, lane = tid & 63;
    if (lane == 0) {
        #pragma unroll
        for (int d = 0; d < 3; ++d) { smx[wid][d] = mx[d]; smn[wid][d] = mn[d]; }
    }
    __syncthreads();
    if (tid == 0) {
        float dm = 0.0f;
        #pragma unroll
        for (int d = 0; d < 3; ++d) {
            float a = -INFINITY, b = INFINITY;
            for (int w = 0; w < 16; ++w) {
                a = fmaxf(a, smx[w][d]); b = fminf(b, smn[w][d]);
            }
            dm = fmaxf(dm, a - b);
        }
        diam_out[0] = dm;
    }
}

// ------------------------------------------------- pack points into float4
__global__ __launch_bounds__(256) void pack_pts_kernel(
    const float* __restrict__ x, const float* __restrict__ y,
    float4* __restrict__ px4, float4* __restrict__ py4)
{
    int gid = blockIdx.x * 256 + threadIdx.x;   // 0..32767
    int sel = gid >> 14;
    int idx = gid & 16383;
    const float* p = sel ? y : x;
    float4 o;
    o.x = p[idx*3+0]; o.y = p[idx*3+1]; o.z = p[idx*3+2]; o.w = 0.0f;
    (sel ? py4 : px4)[idx] = o;
}

// ------------------------------------------------------------- softmin pass
// out[b,i] = -eps * ln2 * log2( sum_j 2^{h2[j] - C_ij * log2e/eps} ) (LSE-stable)
// dir 0: rows = x, cols = y, h = g   |  dir 1: rows = y, cols = x, h = f
__global__ __launch_bounds__(256) void softmin_kernel(
    const float* __restrict__ rows0, const float* __restrict__ rows1,
    const float4* __restrict__ cols0, const float4* __restrict__ cols1,
    const float* __restrict__ h0, const float* __restrict__ h1,
    const float* __restrict__ old0, const float* __restrict__ old1,
    float* __restrict__ out0, float* __restrict__ out1,
    int do_avg, const float* __restrict__ diam_ptr, float scale_k)
{
    __shared__ float4 lds[CHUNK];
    const int dir = blockIdx.z;
    const float*  rows = dir ? rows1 : rows0;
    const float4* cols = dir ? cols1 : cols0;
    const float*  hp   = dir ? h1   : h0;
    const float*  oldf = dir ? old1 : old0;
    float*        outf = dir ? out1 : out0;

    const float diam    = diam_ptr[0];
    const float eps     = fmaxf(diam * scale_k, BLURF);
    const float inv_eps = 1.0f / eps;
    const float nie2    = -LOG2E * inv_eps;

    const int tid  = threadIdx.x, lane = tid & 63, wid = tid >> 6;
    const int i0   = blockIdx.x * ROWS_PER_BLOCK;
    const int b    = i0 >> 13;
    const int ib   = (i0 & (NPTS-1)) + wid * ROWS_PER_WAVE;
    const int rowbase = b * NPTS + ib;

    float px[4], py[4], pz[4];
    #pragma unroll
    for (int r = 0; r < 4; ++r) {
        int o = (rowbase + r) * 3;
        px[r] = rows[o]; py[r] = rows[o+1]; pz[r] = rows[o+2];
    }

    float m[4], s[4];
    #pragma unroll
    for (int r = 0; r < 4; ++r) { m[r] = -INFINITY; s[r] = 0.0f; }

    const float4* csrc = cols + b * NPTS;
    const float*  hsrc = hp ? (hp + b * NPTS) : nullptr;

    for (int c0 = 0; c0 < NPTS; c0 += CHUNK) {
        __syncthreads();
        for (int t = tid; t < CHUNK; t += 256) {
            float4 p = csrc[c0 + t];
            float hv = hsrc ? hsrc[c0 + t] * inv_eps : 0.0f;
            p.w = (BLOGF + hv) * LOG2E;   // h2[j] in base-2 domain
            lds[t] = p;
        }
        __syncthreads();
        // 2 groups of 512 cols; each lane owns 8 cols {g*512 + k*64 + lane}
        #pragma unroll
        for (int g = 0; g < CHUNK/512; ++g) {
            float4 cp[8];
            #pragma unroll
            for (int k = 0; k < 8; ++k) cp[k] = lds[g*512 + k*64 + lane];
            #pragma unroll
            for (int r = 0; r < 4; ++r) {
                float w[8];
                #pragma unroll
                for (int k = 0; k < 8; ++k) {
                    float dx = px[r]-cp[k].x, dy = py[r]-cp[k].y, dz = pz[r]-cp[k].z;
                    float sq = fmaf(dx,dx,fmaf(dy,dy,dz*dz));
                    w[k] = fmaf(FAST_SQRT(sq), nie2, cp[k].w);
                }
                // log-depth group max
                float a01 = fmaxf(w[0],w[1]), a23 = fmaxf(w[2],w[3]);
                float a45 = fmaxf(w[4],w[5]), a67 = fmaxf(w[6],w[7]);
                float gm  = fmaxf(fmaxf(a01,a23), fmaxf(a45,a67));
                float mu  = fmaxf(m[r], gm);
                float scale = exp2f(m[r] - mu);        // exp2(-inf)=0 on first group
                float e0 = exp2f(w[0]-mu) + exp2f(w[1]-mu);
                float e1 = exp2f(w[2]-mu) + exp2f(w[3]-mu);
                float e2 = exp2f(w[4]-mu) + exp2f(w[5]-mu);
                float e3 = exp2f(w[6]-mu) + exp2f(w[7]-mu);
                s[r] = fmaf(s[r], scale, (e0+e1)+(e2+e3));
                m[r] = mu;
            }
        }
    }

    // cross-lane LSE merge (64-lane butterfly)
    #pragma unroll
    for (int r = 0; r < 4; ++r) {
        float mm = m[r], ss = s[r];
        #pragma unroll
        for (int off = 32; off >= 1; off >>= 1) {
            float mo = __shfl_xor(mm, off);
            float so = __shfl_xor(ss, off);
            float mu = fmaxf(mm, mo);
            ss = fmaf(ss, exp2f(mm-mu), so * exp2f(mo-mu));
            mm = mu;
        }
        m[r] = mm; s[r] = ss;
    }

    if (lane == 0) {
        #pragma unroll
        for (int r = 0; r < 4; ++r) {
            float res = -eps * LN2F * (m[r] + log2f(s[r]));
            int oidx = rowbase + r;
            if (do_avg) res = 0.5f * (oldf[oidx] + res);
            outf[oidx] = res;
        }
    }
}

// ----------------------------------------------------------------- reduce
__global__ __launch_bounds__(1024) void reduce_kernel(
    const float* __restrict__ f, const float* __restrict__ g,
    float* __restrict__ out)
{
    int tid = threadIdx.x;
    float acc = 0.0f;
    for (int i = tid; i < NROWS; i += 1024) acc += f[i] + g[i];
    #pragma unroll
    for (int off = 32; off >= 1; off >>= 1) acc += __shfl_xor(acc, off);
    __shared__ float sw[16];
    int wid = tid >> 6, lane = tid & 63;
    if (lane == 0) sw[wid] = acc;
    __syncthreads();
    if (tid == 0) {
        float t = 0.0f;
        for (int w = 0; w < 16; ++w) t += sw[w];
        out[0] = t * (1.0f / (float)NROWS);   // mean over B of (sum a*f + sum b*g)
    }
}

// ----------------------------------------------------------------- launch
extern "C" void kernel_launch(void* const* d_in, const int* in_sizes, int n_in,
                              void* d_out, int out_size, void* d_ws, size_t ws_size,
                              hipStream_t stream)
{
    const float* x = (const float*)d_in[0];
    const float* y = (const float*)d_in[1];
    float* out = (float*)d_out;
    float* ws  = (float*)d_ws;

    float* diam = ws;                    // [16] (aligned pad)
    float* fa = ws + 16;                 // [16384]
    float* ga = fa + NROWS;
    float* fb = ga + NROWS;
    float* gb = fb + NROWS;
    float4* px4 = (float4*)(gb + NROWS); // 16384 float4 (offset 16B-aligned)
    float4* py4 = px4 + NROWS;

    minmax_kernel<<<1, 1024, 0, stream>>>(x, y, diam);
    pack_pts_kernel<<<(NROWS*2)/256, 256, 0, stream>>>(x, y, px4, py4);

    dim3 sgrid(NROWS/ROWS_PER_BLOCK, 1, 2);

    // init: f0 = softmin(eps0, Cxy, b_log), g0 = softmin(eps0, Cyx, a_log)
    softmin_kernel<<<sgrid, 256, 0, stream>>>(x, y, py4, px4,
        nullptr, nullptr, nullptr, nullptr, fa, ga, 0, diam, 1.0f);

    // 96 Jacobi steps with eps annealing: eps_k = max(diam * 0.9^k, blur)
    double sk = 1.0;
    for (int k = 0; k < 96; ++k) {
        softmin_kernel<<<sgrid, 256, 0, stream>>>(x, y, py4, px4,
            ga, fa, fa, ga, fb, gb, 1, diam, (float)sk);
        float* t;
        t = fa; fa = fb; fb = t;
        t = ga; ga = gb; gb = t;
        sk *= 0.9;
    }

    // final extrapolation at eps = blur (scale 0 -> fmax picks BLUR)
    softmin_kernel<<<sgrid, 256, 0, stream>>>(x, y, py4, px4,
        ga, fa, nullptr, nullptr, fb, gb, 0, diam, 0.0f);

    reduce_kernel<<<1, 1024, 0, stream>>>(fb, gb, out);
}